// Round 1
// baseline (286.840 us; speedup 1.0000x reference)
//
#include <hip/hip_runtime.h>
#include <cstdint>
#include <cstddef>

typedef float f32x4 __attribute__((ext_vector_type(4)));
typedef short s16x8 __attribute__((ext_vector_type(8)));
typedef short s16x4 __attribute__((ext_vector_type(4)));

#define MFMA_BF16(a, b, c) __builtin_amdgcn_mfma_f32_16x16x32_bf16((a), (b), (c), 0, 0, 0)

// fp32 -> bf16 round-to-nearest-even (bit manipulation; avoids hip_bf16 struct ABI)
__device__ __forceinline__ unsigned short f2bf(float f) {
  unsigned int u = __float_as_uint(f);
  u += 0x7FFFu + ((u >> 16) & 1u);
  return (unsigned short)(u >> 16);
}

__device__ __forceinline__ s16x8 cvt8(const float* __restrict__ src) {
  const float4 f0 = *(const float4*)src;
  const float4 f1 = *(const float4*)(src + 4);
  s16x8 h;
  h[0] = (short)f2bf(f0.x); h[1] = (short)f2bf(f0.y);
  h[2] = (short)f2bf(f0.z); h[3] = (short)f2bf(f0.w);
  h[4] = (short)f2bf(f1.x); h[5] = (short)f2bf(f1.y);
  h[6] = (short)f2bf(f1.z); h[7] = (short)f2bf(f1.w);
  return h;
}

// ---------------------------------------------------------------------------
// Kernel 1: [Q|K] = x @ w_qkv[0:1024]^T   (v-projection is dead code: the
// reference's replicated source bug builds v2 from k). M=32768 N=1024 K=512.
// Tile 128(M) x 256(N), 8 waves as 2x4, each wave 64x64 (16 mfma frags).
// ---------------------------------------------------------------------------
__global__ __launch_bounds__(512, 2)
void gemm_qk(const float* __restrict__ x, const float* __restrict__ wqkv,
             unsigned short* __restrict__ Q, unsigned short* __restrict__ K) {
  __shared__ unsigned short As[128 * 72];  // +8 pad: bank stride 4(m+q)%32, <=2-way
  __shared__ unsigned short Bs[256 * 72];
  const int t = threadIdx.x;
  const int m0 = blockIdx.y * 128;
  const int n0 = blockIdx.x * 256;  // N fastest grid dim: A-tile L2 reuse
  const int wid = t >> 6, lane = t & 63;
  const int wm = wid >> 2, wn = wid & 3;
  const int nl = lane & 15, quad = lane >> 4;
  const int srow = t >> 3, scol = (t & 7) * 8;

  const f32x4 zero = {0.f, 0.f, 0.f, 0.f};
  f32x4 acc[4][4];
#pragma unroll
  for (int i = 0; i < 4; ++i)
#pragma unroll
    for (int j = 0; j < 4; ++j) acc[i][j] = zero;

  for (int kc = 0; kc < 512; kc += 64) {
#pragma unroll
    for (int p = 0; p < 2; ++p) {
      const int r = srow + p * 64;
      *(s16x8*)&As[r * 72 + scol] = cvt8(x + (size_t)(m0 + r) * 512 + kc + scol);
    }
#pragma unroll
    for (int p = 0; p < 4; ++p) {
      const int r = srow + p * 64;
      *(s16x8*)&Bs[r * 72 + scol] = cvt8(wqkv + (size_t)(n0 + r) * 512 + kc + scol);
    }
    __syncthreads();
#pragma unroll
    for (int ks = 0; ks < 2; ++ks) {
      s16x8 af[4], bf[4];
#pragma unroll
      for (int i = 0; i < 4; ++i)
        af[i] = *(const s16x8*)&As[(wm * 64 + i * 16 + nl) * 72 + ks * 32 + quad * 8];
#pragma unroll
      for (int j = 0; j < 4; ++j)
        bf[j] = *(const s16x8*)&Bs[(wn * 64 + j * 16 + nl) * 72 + ks * 32 + quad * 8];
#pragma unroll
      for (int i = 0; i < 4; ++i)
#pragma unroll
        for (int j = 0; j < 4; ++j) acc[i][j] = MFMA_BF16(af[i], bf[j], acc[i][j]);
    }
    __syncthreads();
  }
  // C/D layout: col = lane&15, row = quad*4 + reg (m89-verified)
#pragma unroll
  for (int i = 0; i < 4; ++i) {
    const int mrow = m0 + wm * 64 + i * 16 + quad * 4;
#pragma unroll
    for (int j = 0; j < 4; ++j) {
      const int n = n0 + wn * 64 + j * 16 + nl;
      unsigned short* dst = (n < 512 ? Q : K) + (size_t)mrow * 512 + (n & 511);
#pragma unroll
      for (int r = 0; r < 4; ++r) dst[(size_t)r * 512] = f2bf(acc[i][j][r]);
    }
  }
}

// ---------------------------------------------------------------------------
// Kernel 2: KWT[b][o][seq] = (K @ w_out^T)^T  — output-projection hoisted in
// front of attention (out@w_out^T == P@(K2@w_out^T)). Transposed store is
// free here: lane's 4 regs are 4 consecutive seq at fixed o -> one 8B store.
// M=32768 N=512 K=512.
// ---------------------------------------------------------------------------
__global__ __launch_bounds__(512, 2)
void gemm_kwt(const unsigned short* __restrict__ K, const float* __restrict__ wout,
              unsigned short* __restrict__ KWT) {
  __shared__ unsigned short As[128 * 72];
  __shared__ unsigned short Bs[256 * 72];
  const int t = threadIdx.x;
  const int m0 = blockIdx.y * 128;
  const int n0 = blockIdx.x * 256;
  const int wid = t >> 6, lane = t & 63;
  const int wm = wid >> 2, wn = wid & 3;
  const int nl = lane & 15, quad = lane >> 4;
  const int srow = t >> 3, scol = (t & 7) * 8;

  const f32x4 zero = {0.f, 0.f, 0.f, 0.f};
  f32x4 acc[4][4];
#pragma unroll
  for (int i = 0; i < 4; ++i)
#pragma unroll
    for (int j = 0; j < 4; ++j) acc[i][j] = zero;

  for (int kc = 0; kc < 512; kc += 64) {
#pragma unroll
    for (int p = 0; p < 2; ++p) {
      const int r = srow + p * 64;
      *(s16x8*)&As[r * 72 + scol] =
          *(const s16x8*)(K + (size_t)(m0 + r) * 512 + kc + scol);
    }
#pragma unroll
    for (int p = 0; p < 4; ++p) {
      const int r = srow + p * 64;
      *(s16x8*)&Bs[r * 72 + scol] = cvt8(wout + (size_t)(n0 + r) * 512 + kc + scol);
    }
    __syncthreads();
#pragma unroll
    for (int ks = 0; ks < 2; ++ks) {
      s16x8 af[4], bf[4];
#pragma unroll
      for (int i = 0; i < 4; ++i)
        af[i] = *(const s16x8*)&As[(wm * 64 + i * 16 + nl) * 72 + ks * 32 + quad * 8];
#pragma unroll
      for (int j = 0; j < 4; ++j)
        bf[j] = *(const s16x8*)&Bs[(wn * 64 + j * 16 + nl) * 72 + ks * 32 + quad * 8];
#pragma unroll
      for (int i = 0; i < 4; ++i)
#pragma unroll
        for (int j = 0; j < 4; ++j) acc[i][j] = MFMA_BF16(af[i], bf[j], acc[i][j]);
    }
    __syncthreads();
  }
#pragma unroll
  for (int i = 0; i < 4; ++i) {
    const int m = m0 + wm * 64 + i * 16 + quad * 4;
    const int b = m >> 13, ns = m & 8191;
#pragma unroll
    for (int j = 0; j < 4; ++j) {
      const int o = n0 + wn * 64 + j * 16 + nl;
      s16x4 h;
#pragma unroll
      for (int r = 0; r < 4; ++r) h[r] = (short)f2bf(acc[i][j][r]);
      *(s16x4*)&KWT[(size_t)(b * 512 + o) * 8192 + ns] = h;
    }
  }
}

// ---------------------------------------------------------------------------
// Kernel 3: per window (b,w): sim = Q·K2^T*scale, causal mask, softmax -> P.
// K2 = [K rows w*128-128 .. +256) (window 0: first half is the zero bucket:
// sim forced to 0 pre-softmax, P forced to 0 post-softmax — equivalent to
// zero K/V rows, so the clamped garbage loads never matter).
// 8 waves as 2(M)x4(N) over the 128x256 sim tile; cross-wave softmax via LDS.
// ---------------------------------------------------------------------------
__global__ __launch_bounds__(512, 2)
void attn_p(const unsigned short* __restrict__ Q, const unsigned short* __restrict__ K,
            unsigned short* __restrict__ P) {
  __shared__ unsigned short Qs[128 * 72];
  __shared__ unsigned short Ks[256 * 72];
  __shared__ float redm[128 * 4];
  __shared__ float reds[128 * 4];
  const int t = threadIdx.x;
  const int bx = blockIdx.x, b = bx >> 6, w = bx & 63;
  const int wid = t >> 6, lane = t & 63;
  const int wm = wid >> 2, wn = wid & 3;
  const int nl = lane & 15, quad = lane >> 4;
  const int srow = t >> 3, scol = (t & 7) * 8;

  const f32x4 zero = {0.f, 0.f, 0.f, 0.f};
  f32x4 acc[4][4];
#pragma unroll
  for (int i = 0; i < 4; ++i)
#pragma unroll
    for (int j = 0; j < 4; ++j) acc[i][j] = zero;

  const unsigned short* Qb = Q + (size_t)(b * 8192 + w * 128) * 512;
  const unsigned short* Kb = K + (size_t)(b * 8192) * 512;

  for (int kc = 0; kc < 512; kc += 64) {
#pragma unroll
    for (int p = 0; p < 2; ++p) {
      const int r = srow + p * 64;
      *(s16x8*)&Qs[r * 72 + scol] = *(const s16x8*)(Qb + (size_t)r * 512 + kc + scol);
    }
#pragma unroll
    for (int p = 0; p < 4; ++p) {
      const int r = srow + p * 64;
      int sq = w * 128 - 128 + r;
      if (sq < 0) sq = 0;  // window 0: garbage, neutralized below
      *(s16x8*)&Ks[r * 72 + scol] = *(const s16x8*)(Kb + (size_t)sq * 512 + kc + scol);
    }
    __syncthreads();
#pragma unroll
    for (int ks = 0; ks < 2; ++ks) {
      s16x8 af[4], bf[4];
#pragma unroll
      for (int i = 0; i < 4; ++i)
        af[i] = *(const s16x8*)&Qs[(wm * 64 + i * 16 + nl) * 72 + ks * 32 + quad * 8];
#pragma unroll
      for (int j = 0; j < 4; ++j)
        bf[j] = *(const s16x8*)&Ks[(wn * 64 + j * 16 + nl) * 72 + ks * 32 + quad * 8];
#pragma unroll
      for (int i = 0; i < 4; ++i)
#pragma unroll
        for (int j = 0; j < 4; ++j) acc[i][j] = MFMA_BF16(af[i], bf[j], acc[i][j]);
    }
    __syncthreads();
  }

  const float scale = 0.04419417382415922f;  // 512^-0.5
  float rmax[4][4];
#pragma unroll
  for (int i = 0; i < 4; ++i) {
#pragma unroll
    for (int r = 0; r < 4; ++r) {
      const int row = wm * 64 + i * 16 + quad * 4 + r;
      float mx = -3.4e38f;
#pragma unroll
      for (int j = 0; j < 4; ++j) {
        const int col = wn * 64 + j * 16 + nl;
        float v = acc[i][j][r] * scale;
        if (col >= 128 && col - 128 > row) v = -3.0e38f;  // causal mask
        if (w == 0 && col < 128) v = 0.0f;                // zero bucket: sim=0
        acc[i][j][r] = v;
        mx = fmaxf(mx, v);
      }
      rmax[i][r] = mx;
    }
  }
#pragma unroll
  for (int off = 1; off < 16; off <<= 1)
#pragma unroll
    for (int i = 0; i < 4; ++i)
#pragma unroll
      for (int r = 0; r < 4; ++r)
        rmax[i][r] = fmaxf(rmax[i][r], __shfl_xor(rmax[i][r], off, 64));
  if (nl == 0) {
#pragma unroll
    for (int i = 0; i < 4; ++i)
#pragma unroll
      for (int r = 0; r < 4; ++r)
        redm[(wm * 64 + i * 16 + quad * 4 + r) * 4 + wn] = rmax[i][r];
  }
  __syncthreads();
  float rsum[4][4];
#pragma unroll
  for (int i = 0; i < 4; ++i) {
#pragma unroll
    for (int r = 0; r < 4; ++r) {
      const f32x4 mv = *(const f32x4*)&redm[(wm * 64 + i * 16 + quad * 4 + r) * 4];
      const float m = fmaxf(fmaxf(mv[0], mv[1]), fmaxf(mv[2], mv[3]));
      rmax[i][r] = m;
      float s = 0.f;
#pragma unroll
      for (int j = 0; j < 4; ++j) {
        const float p = __expf(acc[i][j][r] - m);
        acc[i][j][r] = p;
        s += p;
      }
      rsum[i][r] = s;
    }
  }
#pragma unroll
  for (int off = 1; off < 16; off <<= 1)
#pragma unroll
    for (int i = 0; i < 4; ++i)
#pragma unroll
      for (int r = 0; r < 4; ++r) rsum[i][r] += __shfl_xor(rsum[i][r], off, 64);
  if (nl == 0) {
#pragma unroll
    for (int i = 0; i < 4; ++i)
#pragma unroll
      for (int r = 0; r < 4; ++r)
        reds[(wm * 64 + i * 16 + quad * 4 + r) * 4 + wn] = rsum[i][r];
  }
  __syncthreads();
#pragma unroll
  for (int i = 0; i < 4; ++i) {
#pragma unroll
    for (int r = 0; r < 4; ++r) {
      const int row = wm * 64 + i * 16 + quad * 4 + r;
      const f32x4 sv = *(const f32x4*)&reds[row * 4];
      const float inv = 1.0f / (sv[0] + sv[1] + sv[2] + sv[3]);
#pragma unroll
      for (int j = 0; j < 4; ++j) {
        const int col = wn * 64 + j * 16 + nl;
        float pv = acc[i][j][r] * inv;
        if (w == 0 && col < 128) pv = 0.0f;  // zero V bucket
        P[(size_t)bx * 32768 + (size_t)row * 256 + col] = f2bf(pv);
      }
    }
  }
}

// ---------------------------------------------------------------------------
// Kernel 4: out = P @ KW2 + bias per window.  A = P (128x256, seq-contig),
// B = KWT slice (o rows, seq-contig) -> pure B^T-pattern GEMM over seq (K=256).
// ---------------------------------------------------------------------------
__global__ __launch_bounds__(512, 2)
void gemm_out(const unsigned short* __restrict__ P, const unsigned short* __restrict__ KWT,
              const float* __restrict__ bias, float* __restrict__ out) {
  __shared__ unsigned short As[128 * 72];
  __shared__ unsigned short Bs[256 * 72];
  const int t = threadIdx.x;
  const int wbx = blockIdx.y, b = wbx >> 6, w = wbx & 63;
  const int o0 = blockIdx.x * 256;
  const int wid = t >> 6, lane = t & 63;
  const int wm = wid >> 2, wn = wid & 3;
  const int nl = lane & 15, quad = lane >> 4;
  const int srow = t >> 3, scol = (t & 7) * 8;

  const f32x4 zero = {0.f, 0.f, 0.f, 0.f};
  f32x4 acc[4][4];
#pragma unroll
  for (int i = 0; i < 4; ++i)
#pragma unroll
    for (int j = 0; j < 4; ++j) acc[i][j] = zero;

  const unsigned short* Pw = P + (size_t)wbx * 32768;
  const int seqbase = w * 128 - 128;

  for (int kc = 0; kc < 256; kc += 64) {
#pragma unroll
    for (int p = 0; p < 2; ++p) {
      const int r = srow + p * 64;
      *(s16x8*)&As[r * 72 + scol] = *(const s16x8*)(Pw + (size_t)r * 256 + kc + scol);
    }
#pragma unroll
    for (int p = 0; p < 4; ++p) {
      const int r = srow + p * 64;
      const int o = o0 + r;
      int sq = seqbase + kc + scol;
      if (sq < 0) sq = 0;  // window 0: garbage rows hit zeroed P cols
      *(s16x8*)&Bs[r * 72 + scol] =
          *(const s16x8*)(KWT + (size_t)(b * 512 + o) * 8192 + sq);
    }
    __syncthreads();
#pragma unroll
    for (int ks = 0; ks < 2; ++ks) {
      s16x8 af[4], bf[4];
#pragma unroll
      for (int i = 0; i < 4; ++i)
        af[i] = *(const s16x8*)&As[(wm * 64 + i * 16 + nl) * 72 + ks * 32 + quad * 8];
#pragma unroll
      for (int j = 0; j < 4; ++j)
        bf[j] = *(const s16x8*)&Bs[(wn * 64 + j * 16 + nl) * 72 + ks * 32 + quad * 8];
#pragma unroll
      for (int i = 0; i < 4; ++i)
#pragma unroll
        for (int j = 0; j < 4; ++j) acc[i][j] = MFMA_BF16(af[i], bf[j], acc[i][j]);
    }
    __syncthreads();
  }
#pragma unroll
  for (int i = 0; i < 4; ++i) {
    const int row = wm * 64 + i * 16 + quad * 4;
#pragma unroll
    for (int j = 0; j < 4; ++j) {
      const int o = o0 + wn * 64 + j * 16 + nl;
      const float bo = bias[o];
      float* dst = out + (size_t)(b * 8192 + w * 128 + row) * 512 + o;
#pragma unroll
      for (int r = 0; r < 4; ++r) dst[(size_t)r * 512] = acc[i][j][r] + bo;
    }
  }
}

extern "C" void kernel_launch(void* const* d_in, const int* in_sizes, int n_in,
                              void* d_out, int out_size, void* d_ws, size_t ws_size,
                              hipStream_t stream) {
  const float* x = (const float*)d_in[0];
  const float* w_qkv = (const float*)d_in[1];
  const float* w_out = (const float*)d_in[2];
  const float* b_out = (const float*)d_in[3];
  float* out = (float*)d_out;

  char* ws = (char*)d_ws;
  unsigned short* Q = (unsigned short*)ws;                      // 32768x512 bf16 = 32 MB
  unsigned short* K = (unsigned short*)(ws + (size_t)33554432); // 32 MB
  unsigned short* KWT = (unsigned short*)(ws + (size_t)67108864); // [b][o][seq] 32 MB
  unsigned short* P = (unsigned short*)(ws + (size_t)100663296);  // 256 windows x128x256 = 16 MB

  const dim3 blk(512);
  gemm_qk<<<dim3(4, 256), blk, 0, stream>>>(x, w_qkv, Q, K);
  gemm_kwt<<<dim3(2, 256), blk, 0, stream>>>(K, w_out, KWT);
  attn_p<<<dim3(256), blk, 0, stream>>>(Q, K, P);
  gemm_out<<<dim3(2, 256), blk, 0, stream>>>(P, KWT, b_out, out);
}

// Round 2
// 262.390 us; speedup vs baseline: 1.0932x; 1.0932x over previous
//
#include <hip/hip_runtime.h>
#include <cstdint>
#include <cstddef>

typedef float f32x4 __attribute__((ext_vector_type(4)));
typedef short s16x8 __attribute__((ext_vector_type(8)));
typedef short s16x4 __attribute__((ext_vector_type(4)));

#define MFMA_BF16(a, b, c) __builtin_amdgcn_mfma_f32_16x16x32_bf16((a), (b), (c), 0, 0, 0)

// async global->LDS DMA, 16B per lane: data lands at ldsbase + lane*16.
// LDS base must be wave-uniform; global address is per-lane.
#define GLD16(g, l)                                                            \
  __builtin_amdgcn_global_load_lds(                                            \
      (const __attribute__((address_space(1))) void*)(g),                      \
      (__attribute__((address_space(3))) void*)(l), 16, 0, 0)

// fp32 -> bf16 round-to-nearest-even
__device__ __forceinline__ unsigned short f2bf(float f) {
  unsigned int u = __float_as_uint(f);
  u += 0x7FFFu + ((u >> 16) & 1u);
  return (unsigned short)(u >> 16);
}

__device__ __forceinline__ s16x8 cvt8(const float* __restrict__ src) {
  const float4 f0 = *(const float4*)src;
  const float4 f1 = *(const float4*)(src + 4);
  s16x8 h;
  h[0] = (short)f2bf(f0.x); h[1] = (short)f2bf(f0.y);
  h[2] = (short)f2bf(f0.z); h[3] = (short)f2bf(f0.w);
  h[4] = (short)f2bf(f1.x); h[5] = (short)f2bf(f1.y);
  h[6] = (short)f2bf(f1.z); h[7] = (short)f2bf(f1.w);
  return h;
}

// ---------------------------------------------------------------------------
// Kernel 0: one-shot fp32->bf16 of x, w_qkv[0:1024] (v-proj rows are dead
// code: reference builds v2 from k), and w_out. Memory-bound.
// ---------------------------------------------------------------------------
#define XN 16777216   // 4*8192*512
#define WQN 524288    // 1024*512
#define WON 262144    // 512*512
__global__ __launch_bounds__(256)
void cvt_bf16(const float* __restrict__ x, const float* __restrict__ wqkv,
              const float* __restrict__ wout, unsigned short* __restrict__ xb,
              unsigned short* __restrict__ wb, unsigned short* __restrict__ wob) {
  const size_t i = (size_t)(blockIdx.x * 256 + threadIdx.x) * 8;
  const float* src;
  unsigned short* dst;
  if (i < XN) { src = x + i; dst = xb + i; }
  else if (i < XN + WQN) { src = wqkv + (i - XN); dst = wb + (i - XN); }
  else { src = wout + (i - XN - WQN); dst = wob + (i - XN - WQN); }
  *(s16x8*)dst = cvt8(src);
}

// ---------------------------------------------------------------------------
// Kernel 1: [Q|K] = xb @ wb^T. M=32768 N=1024 K=512. m97 structure: 128x128
// tile, 256 threads (4 waves 2x2, each 64x64), BK=64, global_load_lds + XOR
// swizzle (physBlk = logBlk ^ (row&7)) -> conflict-free b128 fragment reads.
// ---------------------------------------------------------------------------
__global__ __launch_bounds__(256)
void gemm_qk(const unsigned short* __restrict__ xb, const unsigned short* __restrict__ wb,
             unsigned short* __restrict__ Q, unsigned short* __restrict__ K) {
  __shared__ unsigned short As[128 * 64];
  __shared__ unsigned short Bs[128 * 64];
  const int t = threadIdx.x;
  const int lane = t & 63, wid = t >> 6;
  const int wm = wid >> 1, wn = wid & 1;
  const int nl = lane & 15, quad = lane >> 4;
  const int m0 = blockIdx.y * 128, n0 = blockIdx.x * 128;
  const int sub = lane >> 3;              // row within 8-row group
  const int lblk = (lane & 7) ^ sub;      // xor-swizzled 16B block

  const f32x4 zero = {0.f, 0.f, 0.f, 0.f};
  f32x4 acc[4][4];
#pragma unroll
  for (int i = 0; i < 4; ++i)
#pragma unroll
    for (int j = 0; j < 4; ++j) acc[i][j] = zero;

  const unsigned short* gA = xb + (size_t)(m0 + wid * 32 + sub) * 512 + lblk * 8;
  const unsigned short* gB = wb + (size_t)(n0 + wid * 32 + sub) * 512 + lblk * 8;

  for (int kc = 0; kc < 512; kc += 64) {
#pragma unroll
    for (int ii = 0; ii < 4; ++ii) {
      GLD16(gA + kc + (size_t)(ii * 8) * 512, &As[(wid * 32 + ii * 8) * 64]);
      GLD16(gB + kc + (size_t)(ii * 8) * 512, &Bs[(wid * 32 + ii * 8) * 64]);
    }
    __syncthreads();
#pragma unroll
    for (int ks = 0; ks < 2; ++ks) {
      s16x8 af[4], bf[4];
#pragma unroll
      for (int i = 0; i < 4; ++i)
        af[i] = *(const s16x8*)&As[(wm * 64 + i * 16 + nl) * 64 +
                                   (((ks * 4 + quad) ^ (nl & 7)) * 8)];
#pragma unroll
      for (int j = 0; j < 4; ++j)
        bf[j] = *(const s16x8*)&Bs[(wn * 64 + j * 16 + nl) * 64 +
                                   (((ks * 4 + quad) ^ (nl & 7)) * 8)];
#pragma unroll
      for (int i = 0; i < 4; ++i)
#pragma unroll
        for (int j = 0; j < 4; ++j) acc[i][j] = MFMA_BF16(af[i], bf[j], acc[i][j]);
    }
    __syncthreads();
  }
#pragma unroll
  for (int i = 0; i < 4; ++i) {
    const int mrow = m0 + wm * 64 + i * 16 + quad * 4;
#pragma unroll
    for (int j = 0; j < 4; ++j) {
      const int n = n0 + wn * 64 + j * 16 + nl;
      unsigned short* dst = (n < 512 ? Q : K) + (size_t)mrow * 512 + (n & 511);
#pragma unroll
      for (int r = 0; r < 4; ++r) dst[(size_t)r * 512] = f2bf(acc[i][j][r]);
    }
  }
}

// ---------------------------------------------------------------------------
// Kernel 2: KWT[b][o][seq] = (K @ wob^T)^T — output projection hoisted before
// attention. Same m97 structure; transposed epilogue is one 8B store/frag.
// ---------------------------------------------------------------------------
__global__ __launch_bounds__(256)
void gemm_kwt(const unsigned short* __restrict__ K, const unsigned short* __restrict__ wob,
              unsigned short* __restrict__ KWT) {
  __shared__ unsigned short As[128 * 64];
  __shared__ unsigned short Bs[128 * 64];
  const int t = threadIdx.x;
  const int lane = t & 63, wid = t >> 6;
  const int wm = wid >> 1, wn = wid & 1;
  const int nl = lane & 15, quad = lane >> 4;
  const int m0 = blockIdx.y * 128, n0 = blockIdx.x * 128;
  const int sub = lane >> 3, lblk = (lane & 7) ^ sub;

  const f32x4 zero = {0.f, 0.f, 0.f, 0.f};
  f32x4 acc[4][4];
#pragma unroll
  for (int i = 0; i < 4; ++i)
#pragma unroll
    for (int j = 0; j < 4; ++j) acc[i][j] = zero;

  const unsigned short* gA = K + (size_t)(m0 + wid * 32 + sub) * 512 + lblk * 8;
  const unsigned short* gB = wob + (size_t)(n0 + wid * 32 + sub) * 512 + lblk * 8;

  for (int kc = 0; kc < 512; kc += 64) {
#pragma unroll
    for (int ii = 0; ii < 4; ++ii) {
      GLD16(gA + kc + (size_t)(ii * 8) * 512, &As[(wid * 32 + ii * 8) * 64]);
      GLD16(gB + kc + (size_t)(ii * 8) * 512, &Bs[(wid * 32 + ii * 8) * 64]);
    }
    __syncthreads();
#pragma unroll
    for (int ks = 0; ks < 2; ++ks) {
      s16x8 af[4], bf[4];
#pragma unroll
      for (int i = 0; i < 4; ++i)
        af[i] = *(const s16x8*)&As[(wm * 64 + i * 16 + nl) * 64 +
                                   (((ks * 4 + quad) ^ (nl & 7)) * 8)];
#pragma unroll
      for (int j = 0; j < 4; ++j)
        bf[j] = *(const s16x8*)&Bs[(wn * 64 + j * 16 + nl) * 64 +
                                   (((ks * 4 + quad) ^ (nl & 7)) * 8)];
#pragma unroll
      for (int i = 0; i < 4; ++i)
#pragma unroll
        for (int j = 0; j < 4; ++j) acc[i][j] = MFMA_BF16(af[i], bf[j], acc[i][j]);
    }
    __syncthreads();
  }
#pragma unroll
  for (int i = 0; i < 4; ++i) {
    const int m = m0 + wm * 64 + i * 16 + quad * 4;
    const int b = m >> 13, ns = m & 8191;
#pragma unroll
    for (int j = 0; j < 4; ++j) {
      const int o = n0 + wn * 64 + j * 16 + nl;
      s16x4 h;
#pragma unroll
      for (int r = 0; r < 4; ++r) h[r] = (short)f2bf(acc[i][j][r]);
      *(s16x4*)&KWT[(size_t)(b * 512 + o) * 8192 + ns] = h;
    }
  }
}

// ---------------------------------------------------------------------------
// Kernel 3: per window: sim = Q·K2^T*scale, mask, softmax -> P (bf16).
// 8 waves 2x4 over the 128x256 sim tile; staging now via global_load_lds.
// Window 0's zero bucket: clamped loads neutralized pre/post softmax.
// ---------------------------------------------------------------------------
__global__ __launch_bounds__(512)
void attn_p(const unsigned short* __restrict__ Q, const unsigned short* __restrict__ K,
            unsigned short* __restrict__ P) {
  __shared__ unsigned short Qs[128 * 64];
  __shared__ unsigned short Ks[256 * 64];
  __shared__ float redm[128 * 4];
  __shared__ float reds[128 * 4];
  const int t = threadIdx.x;
  const int bx = blockIdx.x, b = bx >> 6, w = bx & 63;
  const int lane = t & 63, wid = t >> 6;
  const int wm = wid >> 2, wn = wid & 3;
  const int nl = lane & 15, quad = lane >> 4;
  const int sub = lane >> 3, lblk = (lane & 7) ^ sub;

  const f32x4 zero = {0.f, 0.f, 0.f, 0.f};
  f32x4 acc[4][4];
#pragma unroll
  for (int i = 0; i < 4; ++i)
#pragma unroll
    for (int j = 0; j < 4; ++j) acc[i][j] = zero;

  const unsigned short* Qb = Q + (size_t)(b * 8192 + w * 128) * 512;
  const unsigned short* Kb = K + (size_t)(b * 8192) * 512;

  for (int kc = 0; kc < 512; kc += 64) {
#pragma unroll
    for (int ii = 0; ii < 2; ++ii)
      GLD16(Qb + (size_t)(wid * 16 + ii * 8 + sub) * 512 + kc + lblk * 8,
            &Qs[(wid * 16 + ii * 8) * 64]);
#pragma unroll
    for (int ii = 0; ii < 4; ++ii) {
      int sq = w * 128 - 128 + wid * 32 + ii * 8 + sub;
      if (sq < 0) sq = 0;  // window 0: garbage, neutralized below
      GLD16(Kb + (size_t)sq * 512 + kc + lblk * 8, &Ks[(wid * 32 + ii * 8) * 64]);
    }
    __syncthreads();
#pragma unroll
    for (int ks = 0; ks < 2; ++ks) {
      s16x8 af[4], bf[4];
#pragma unroll
      for (int i = 0; i < 4; ++i)
        af[i] = *(const s16x8*)&Qs[(wm * 64 + i * 16 + nl) * 64 +
                                   (((ks * 4 + quad) ^ (nl & 7)) * 8)];
#pragma unroll
      for (int j = 0; j < 4; ++j)
        bf[j] = *(const s16x8*)&Ks[(wn * 64 + j * 16 + nl) * 64 +
                                   (((ks * 4 + quad) ^ (nl & 7)) * 8)];
#pragma unroll
      for (int i = 0; i < 4; ++i)
#pragma unroll
        for (int j = 0; j < 4; ++j) acc[i][j] = MFMA_BF16(af[i], bf[j], acc[i][j]);
    }
    __syncthreads();
  }

  const float scale = 0.04419417382415922f;  // 512^-0.5
  float rmax[4][4];
#pragma unroll
  for (int i = 0; i < 4; ++i) {
#pragma unroll
    for (int r = 0; r < 4; ++r) {
      const int row = wm * 64 + i * 16 + quad * 4 + r;
      float mx = -3.4e38f;
#pragma unroll
      for (int j = 0; j < 4; ++j) {
        const int col = wn * 64 + j * 16 + nl;
        float v = acc[i][j][r] * scale;
        if (col >= 128 && col - 128 > row) v = -3.0e38f;  // causal mask
        if (w == 0 && col < 128) v = 0.0f;                // zero bucket: sim=0
        acc[i][j][r] = v;
        mx = fmaxf(mx, v);
      }
      rmax[i][r] = mx;
    }
  }
#pragma unroll
  for (int off = 1; off < 16; off <<= 1)
#pragma unroll
    for (int i = 0; i < 4; ++i)
#pragma unroll
      for (int r = 0; r < 4; ++r)
        rmax[i][r] = fmaxf(rmax[i][r], __shfl_xor(rmax[i][r], off, 64));
  if (nl == 0) {
#pragma unroll
    for (int i = 0; i < 4; ++i)
#pragma unroll
      for (int r = 0; r < 4; ++r)
        redm[(wm * 64 + i * 16 + quad * 4 + r) * 4 + wn] = rmax[i][r];
  }
  __syncthreads();
  float rsum[4][4];
#pragma unroll
  for (int i = 0; i < 4; ++i) {
#pragma unroll
    for (int r = 0; r < 4; ++r) {
      const f32x4 mv = *(const f32x4*)&redm[(wm * 64 + i * 16 + quad * 4 + r) * 4];
      const float m = fmaxf(fmaxf(mv[0], mv[1]), fmaxf(mv[2], mv[3]));
      float s = 0.f;
#pragma unroll
      for (int j = 0; j < 4; ++j) {
        const float p = __expf(acc[i][j][r] - m);
        acc[i][j][r] = p;
        s += p;
      }
      rsum[i][r] = s;
    }
  }
#pragma unroll
  for (int off = 1; off < 16; off <<= 1)
#pragma unroll
    for (int i = 0; i < 4; ++i)
#pragma unroll
      for (int r = 0; r < 4; ++r) rsum[i][r] += __shfl_xor(rsum[i][r], off, 64);
  if (nl == 0) {
#pragma unroll
    for (int i = 0; i < 4; ++i)
#pragma unroll
      for (int r = 0; r < 4; ++r)
        reds[(wm * 64 + i * 16 + quad * 4 + r) * 4 + wn] = rsum[i][r];
  }
  __syncthreads();
#pragma unroll
  for (int i = 0; i < 4; ++i) {
#pragma unroll
    for (int r = 0; r < 4; ++r) {
      const int row = wm * 64 + i * 16 + quad * 4 + r;
      const f32x4 sv = *(const f32x4*)&reds[row * 4];
      const float inv = 1.0f / (sv[0] + sv[1] + sv[2] + sv[3]);
#pragma unroll
      for (int j = 0; j < 4; ++j) {
        const int col = wn * 64 + j * 16 + nl;
        float pv = acc[i][j][r] * inv;
        if (w == 0 && col < 128) pv = 0.0f;  // zero V bucket
        P[(size_t)bx * 32768 + (size_t)row * 256 + col] = f2bf(pv);
      }
    }
  }
}

// ---------------------------------------------------------------------------
// Kernel 4: out = P @ KW2 + bias per window (K=256 over seq). Same staging.
// ---------------------------------------------------------------------------
__global__ __launch_bounds__(512)
void gemm_out(const unsigned short* __restrict__ P, const unsigned short* __restrict__ KWT,
              const float* __restrict__ bias, float* __restrict__ out) {
  __shared__ unsigned short As[128 * 64];
  __shared__ unsigned short Bs[256 * 64];
  const int t = threadIdx.x;
  const int wbx = blockIdx.y, b = wbx >> 6, w = wbx & 63;
  const int o0 = blockIdx.x * 256;
  const int lane = t & 63, wid = t >> 6;
  const int wm = wid >> 2, wn = wid & 3;
  const int nl = lane & 15, quad = lane >> 4;
  const int sub = lane >> 3, lblk = (lane & 7) ^ sub;

  const f32x4 zero = {0.f, 0.f, 0.f, 0.f};
  f32x4 acc[4][4];
#pragma unroll
  for (int i = 0; i < 4; ++i)
#pragma unroll
    for (int j = 0; j < 4; ++j) acc[i][j] = zero;

  const unsigned short* Pw = P + (size_t)wbx * 32768;
  const int seqbase = w * 128 - 128;

  for (int kc = 0; kc < 256; kc += 64) {
#pragma unroll
    for (int ii = 0; ii < 2; ++ii)
      GLD16(Pw + (size_t)(wid * 16 + ii * 8 + sub) * 256 + kc + lblk * 8,
            &As[(wid * 16 + ii * 8) * 64]);
    int sq = seqbase + kc + lblk * 8;
    if (sq < 0) sq = 0;  // window 0: garbage k-cols hit zeroed P cols
#pragma unroll
    for (int ii = 0; ii < 4; ++ii)
      GLD16(KWT + (size_t)(b * 512 + o0 + wid * 32 + ii * 8 + sub) * 8192 + sq,
            &Bs[(wid * 32 + ii * 8) * 64]);
    __syncthreads();
#pragma unroll
    for (int ks = 0; ks < 2; ++ks) {
      s16x8 af[4], bf[4];
#pragma unroll
      for (int i = 0; i < 4; ++i)
        af[i] = *(const s16x8*)&As[(wm * 64 + i * 16 + nl) * 64 +
                                   (((ks * 4 + quad) ^ (nl & 7)) * 8)];
#pragma unroll
      for (int j = 0; j < 4; ++j)
        bf[j] = *(const s16x8*)&Bs[(wn * 64 + j * 16 + nl) * 64 +
                                   (((ks * 4 + quad) ^ (nl & 7)) * 8)];
#pragma unroll
      for (int i = 0; i < 4; ++i)
#pragma unroll
        for (int j = 0; j < 4; ++j) acc[i][j] = MFMA_BF16(af[i], bf[j], acc[i][j]);
    }
    __syncthreads();
  }
#pragma unroll
  for (int i = 0; i < 4; ++i) {
    const int row = wm * 64 + i * 16 + quad * 4;
#pragma unroll
    for (int j = 0; j < 4; ++j) {
      const int o = o0 + wn * 64 + j * 16 + nl;
      const float bo = bias[o];
      float* dst = out + (size_t)(b * 8192 + w * 128 + row) * 512 + o;
#pragma unroll
      for (int r = 0; r < 4; ++r) dst[(size_t)r * 512] = acc[i][j][r] + bo;
    }
  }
}

extern "C" void kernel_launch(void* const* d_in, const int* in_sizes, int n_in,
                              void* d_out, int out_size, void* d_ws, size_t ws_size,
                              hipStream_t stream) {
  const float* x = (const float*)d_in[0];
  const float* w_qkv = (const float*)d_in[1];
  const float* w_out = (const float*)d_in[2];
  const float* b_out = (const float*)d_in[3];
  float* out = (float*)d_out;

  char* ws = (char*)d_ws;
  // Aliased layout (112 MB total):
  //   Q   @   0 .. 32MB
  //   K   @ 32MB .. 64MB
  //   xb  @ 64MB .. 96MB   (dead after gemm_qk)
  //   KWT @ 64MB .. 96MB   (written by gemm_kwt, after xb dead)
  //   P   @ 96MB ..112MB   (written by attn_p)
  //   wb  @ 96MB .. 97MB   (dead after gemm_qk, before P written)
  //   wob @ 97MB .. 97.5MB (dead after gemm_kwt, before P written)
  unsigned short* Q = (unsigned short*)ws;
  unsigned short* K = (unsigned short*)(ws + (size_t)33554432);
  unsigned short* xb = (unsigned short*)(ws + (size_t)67108864);
  unsigned short* KWT = (unsigned short*)(ws + (size_t)67108864);
  unsigned short* P = (unsigned short*)(ws + (size_t)100663296);
  unsigned short* wb = (unsigned short*)(ws + (size_t)100663296);
  unsigned short* wob = (unsigned short*)(ws + (size_t)100663296 + 1048576);

  cvt_bf16<<<dim3(8576), dim3(256), 0, stream>>>(x, w_qkv, w_out, xb, wb, wob);
  gemm_qk<<<dim3(8, 256), dim3(256), 0, stream>>>(xb, wb, Q, K);
  gemm_kwt<<<dim3(4, 256), dim3(256), 0, stream>>>(K, wob, KWT);
  attn_p<<<dim3(256), dim3(512), 0, stream>>>(Q, K, P);
  gemm_out<<<dim3(2, 256), dim3(512), 0, stream>>>(P, KWT, b_out, out);
}